// Round 7
// baseline (143.359 us; speedup 1.0000x reference)
//
#include <hip/hip_runtime.h>

// Householder reflection per row: out = z - 2 * v * (v.z) / (v.v)
// B = 1048576 rows, L = 64 fp32 per row.
//
// Ablation of R5: NT hint on the STORE only (out never re-read -> no L3
// allocation). v and z use regular loads (both may allocate in L3; aggregate
// FETCH unchanged by capacity argument -- this tests whether the NT read
// path itself was throttling HBM read efficiency).
typedef float f32x4 __attribute__((ext_vector_type(4)));

__global__ void __launch_bounds__(256) HF_28063316312693_kernel(
        const float* __restrict__ v,
        const float* __restrict__ z,
        float* __restrict__ out) {
    const int tid    = blockIdx.x * blockDim.x + threadIdx.x;
    const int wave   = tid >> 6;       // owns rows [wave*16, wave*16+16)
    const int lane   = tid & 63;
    const int l4     = lane & 15;      // float4 slot within the row
    const int subrow = lane >> 4;      // 0..3

    const size_t b0 = ((size_t)wave * 16 + subrow) * 64 + (size_t)l4 * 4;

    const f32x4* vp = reinterpret_cast<const f32x4*>(v + b0);
    const f32x4* zp = reinterpret_cast<const f32x4*>(z + b0);

    const f32x4 va = vp[0];
    const f32x4 vb = vp[64];
    const f32x4 vc = vp[128];
    const f32x4 vd = vp[192];
    const f32x4 za = zp[0];
    const f32x4 zb = zp[64];
    const f32x4 zc = zp[128];
    const f32x4 zd = zp[192];

    float vza = va.x * za.x + va.y * za.y + va.z * za.z + va.w * za.w;
    float nna = va.x * va.x + va.y * va.y + va.z * va.z + va.w * va.w;
    float vzb = vb.x * zb.x + vb.y * zb.y + vb.z * zb.z + vb.w * zb.w;
    float nnb = vb.x * vb.x + vb.y * vb.y + vb.z * vb.z + vb.w * vb.w;
    float vzc = vc.x * zc.x + vc.y * zc.y + vc.z * zc.z + vc.w * zc.w;
    float nnc = vc.x * vc.x + vc.y * vc.y + vc.z * vc.z + vc.w * vc.w;
    float vzd = vd.x * zd.x + vd.y * zd.y + vd.z * zd.z + vd.w * zd.w;
    float nnd = vd.x * vd.x + vd.y * vd.y + vd.z * vd.z + vd.w * vd.w;

    #pragma unroll
    for (int off = 1; off < 16; off <<= 1) {
        vza += __shfl_xor(vza, off, 64);
        nna += __shfl_xor(nna, off, 64);
        vzb += __shfl_xor(vzb, off, 64);
        nnb += __shfl_xor(nnb, off, 64);
        vzc += __shfl_xor(vzc, off, 64);
        nnc += __shfl_xor(nnc, off, 64);
        vzd += __shfl_xor(vzd, off, 64);
        nnd += __shfl_xor(nnd, off, 64);
    }

    const float sa = -2.0f * vza / nna;
    const float sb = -2.0f * vzb / nnb;
    const float sc = -2.0f * vzc / nnc;
    const float sd = -2.0f * vzd / nnd;

    f32x4 oa, ob, oc, od;
    oa.x = fmaf(sa, va.x, za.x); oa.y = fmaf(sa, va.y, za.y);
    oa.z = fmaf(sa, va.z, za.z); oa.w = fmaf(sa, va.w, za.w);
    ob.x = fmaf(sb, vb.x, zb.x); ob.y = fmaf(sb, vb.y, zb.y);
    ob.z = fmaf(sb, vb.z, zb.z); ob.w = fmaf(sb, vb.w, zb.w);
    oc.x = fmaf(sc, vc.x, zc.x); oc.y = fmaf(sc, vc.y, zc.y);
    oc.z = fmaf(sc, vc.z, zc.z); oc.w = fmaf(sc, vc.w, zc.w);
    od.x = fmaf(sd, vd.x, zd.x); od.y = fmaf(sd, vd.y, zd.y);
    od.z = fmaf(sd, vd.z, zd.z); od.w = fmaf(sd, vd.w, zd.w);

    f32x4* op = reinterpret_cast<f32x4*>(out + b0);
    __builtin_nontemporal_store(oa, op);
    __builtin_nontemporal_store(ob, op + 64);
    __builtin_nontemporal_store(oc, op + 128);
    __builtin_nontemporal_store(od, op + 192);
}

extern "C" void kernel_launch(void* const* d_in, const int* in_sizes, int n_in,
                              void* d_out, int out_size, void* d_ws, size_t ws_size,
                              hipStream_t stream) {
    const float* v = (const float*)d_in[0];
    const float* z = (const float*)d_in[1];
    float* out = (float*)d_out;
    const int B = in_sizes[0] / 64;  // 1048576

    const int block = 256;
    const int grid = B / 64;  // 64 rows per block, exact fit

    HF_28063316312693_kernel<<<grid, block, 0, stream>>>(v, z, out);
}

// Round 8
// 116.549 us; speedup vs baseline: 1.2300x; 1.2300x over previous
//
#include <hip/hip_runtime.h>

// Householder reflection per row: out = z - 2 * v * (v.z) / (v.v)
// B = 1048576 rows, L = 64 fp32 per row.
//
// Best configuration (R5): 16 lanes/row, 4 rows per thread, 1 KiB contiguous
// wave loads. NT hints: v streamed (bypass L3 retention), out streamed (no
// L3 allocation) -> z stays deterministically L3-resident (256 MiB = L3).
// R7 ablation showed NT on the v-load is load-bearing (+18% vs store-only):
// identical FETCH_SIZE, but deterministic residency avoids L3 thrash churn.
typedef float f32x4 __attribute__((ext_vector_type(4)));

__global__ void __launch_bounds__(256) HF_28063316312693_kernel(
        const float* __restrict__ v,
        const float* __restrict__ z,
        float* __restrict__ out) {
    const int tid    = blockIdx.x * blockDim.x + threadIdx.x;
    const int wave   = tid >> 6;       // owns rows [wave*16, wave*16+16)
    const int lane   = tid & 63;
    const int l4     = lane & 15;      // float4 slot within the row
    const int subrow = lane >> 4;      // 0..3

    const size_t b0 = ((size_t)wave * 16 + subrow) * 64 + (size_t)l4 * 4;

    const f32x4* vp = reinterpret_cast<const f32x4*>(v + b0);
    const f32x4* zp = reinterpret_cast<const f32x4*>(z + b0);

    const f32x4 va = __builtin_nontemporal_load(vp);
    const f32x4 vb = __builtin_nontemporal_load(vp + 64);   // +256 floats
    const f32x4 vc = __builtin_nontemporal_load(vp + 128);  // +512 floats
    const f32x4 vd = __builtin_nontemporal_load(vp + 192);  // +768 floats
    const f32x4 za = zp[0];
    const f32x4 zb = zp[64];
    const f32x4 zc = zp[128];
    const f32x4 zd = zp[192];

    float vza = va.x * za.x + va.y * za.y + va.z * za.z + va.w * za.w;
    float nna = va.x * va.x + va.y * va.y + va.z * va.z + va.w * va.w;
    float vzb = vb.x * zb.x + vb.y * zb.y + vb.z * zb.z + vb.w * zb.w;
    float nnb = vb.x * vb.x + vb.y * vb.y + vb.z * vb.z + vb.w * vb.w;
    float vzc = vc.x * zc.x + vc.y * zc.y + vc.z * zc.z + vc.w * zc.w;
    float nnc = vc.x * vc.x + vc.y * vc.y + vc.z * vc.z + vc.w * vc.w;
    float vzd = vd.x * zd.x + vd.y * zd.y + vd.z * zd.z + vd.w * zd.w;
    float nnd = vd.x * vd.x + vd.y * vd.y + vd.z * vd.z + vd.w * vd.w;

    #pragma unroll
    for (int off = 1; off < 16; off <<= 1) {
        vza += __shfl_xor(vza, off, 64);
        nna += __shfl_xor(nna, off, 64);
        vzb += __shfl_xor(vzb, off, 64);
        nnb += __shfl_xor(nnb, off, 64);
        vzc += __shfl_xor(vzc, off, 64);
        nnc += __shfl_xor(nnc, off, 64);
        vzd += __shfl_xor(vzd, off, 64);
        nnd += __shfl_xor(nnd, off, 64);
    }

    const float sa = -2.0f * vza / nna;
    const float sb = -2.0f * vzb / nnb;
    const float sc = -2.0f * vzc / nnc;
    const float sd = -2.0f * vzd / nnd;

    f32x4 oa, ob, oc, od;
    oa.x = fmaf(sa, va.x, za.x); oa.y = fmaf(sa, va.y, za.y);
    oa.z = fmaf(sa, va.z, za.z); oa.w = fmaf(sa, va.w, za.w);
    ob.x = fmaf(sb, vb.x, zb.x); ob.y = fmaf(sb, vb.y, zb.y);
    ob.z = fmaf(sb, vb.z, zb.z); ob.w = fmaf(sb, vb.w, zb.w);
    oc.x = fmaf(sc, vc.x, zc.x); oc.y = fmaf(sc, vc.y, zc.y);
    oc.z = fmaf(sc, vc.z, zc.z); oc.w = fmaf(sc, vc.w, zc.w);
    od.x = fmaf(sd, vd.x, zd.x); od.y = fmaf(sd, vd.y, zd.y);
    od.z = fmaf(sd, vd.z, zd.z); od.w = fmaf(sd, vd.w, zd.w);

    f32x4* op = reinterpret_cast<f32x4*>(out + b0);
    __builtin_nontemporal_store(oa, op);
    __builtin_nontemporal_store(ob, op + 64);
    __builtin_nontemporal_store(oc, op + 128);
    __builtin_nontemporal_store(od, op + 192);
}

extern "C" void kernel_launch(void* const* d_in, const int* in_sizes, int n_in,
                              void* d_out, int out_size, void* d_ws, size_t ws_size,
                              hipStream_t stream) {
    const float* v = (const float*)d_in[0];
    const float* z = (const float*)d_in[1];
    float* out = (float*)d_out;
    const int B = in_sizes[0] / 64;  // 1048576

    const int block = 256;
    const int grid = B / 64;  // 64 rows per block, exact fit

    HF_28063316312693_kernel<<<grid, block, 0, stream>>>(v, z, out);
}